// Round 16
// baseline (81.655 us; speedup 1.0000x reference)
//
#include <hip/hip_runtime.h>
#include <hip/hip_bf16.h>

// GCN layer: out = spmm(adj, x @ W) + bias
// Inputs: x[50000,128] f32, weight[128,128] f32, bias[128] f32,
//         edge_vals[625000] f32, edge_rows[625000] i32, edge_cols[625000] i32
// Output: out[50000,128] f32
//
// Round 16 pipeline (4 dispatches):
//   init      : blocks 0-63 wconv (wt = bf16(w^T)); block 64 zeroes lenC
//   k1        : 306 blocks coarse-bin 2048 edges each into 98 slabs of
//               512 rows (shfl-scan, segment-flushed)
//   splitgemm : merged dispatch: blocks [0,98) row-sort each slab -> CSR;
//               blocks [98,1661) MFMA gemm (32 rows/block, 8 waves)
//   bspmm     : row per HALF-wave; 8-deep masked record rounds -> 16
//               records in flight per wave (2x r14), no shuffle epilogue.
// Lessons kept: float atomics on __shared__ lower to the flat path (r7/8);
// per-record row switch if-converts to ~50 VALU/record (r12); fine-grained
// direct global binning = random 8-B scatter (r5).

#define F_DIM 128

#define NBC 98                  // coarse buckets: row >> 9
#define SLABC 7360              // records per coarse slab (mean 6378, +12s)
#define NROW_PAD (NBC * 512)    // 50176

#define BIN_T 256
#define BIN_EPT 8
#define BIN_CHUNK (BIN_T * BIN_EPT)     // 2048 edges per block

#define SPLIT_T 512
#define SPLIT_EPT 15            // 512*15 = 7680 >= SLABC
#define GEMM_BLKS 1563          // ceil(50000/32)

typedef short bf16x8 __attribute__((ext_vector_type(8)));
typedef float f32x4 __attribute__((ext_vector_type(4)));

__device__ __forceinline__ unsigned short f2bf(float f) {
    unsigned int u = __float_as_uint(f);
    u += 0x7FFFu + ((u >> 16) & 1u);   // round-to-nearest-even
    return (unsigned short)(u >> 16);
}

// ---- init: wconv (blocks 0-63) + zero lenC (block 64) --------------------
__global__ void __launch_bounds__(256)
init_kernel(const float* __restrict__ w, unsigned short* __restrict__ wt,
            int* __restrict__ lenC) {
    if (blockIdx.x == 64) {
        if (threadIdx.x < NBC) lenC[threadIdx.x] = 0;
        return;
    }
    int idx = blockIdx.x * 256 + threadIdx.x;
    int n = idx >> 7, k = idx & 127;
    wt[n * F_DIM + k] = f2bf(w[k * F_DIM + n]);
}

// ---- k1: coarse bin into 98 slabs of 512 rows ----------------------------
__global__ void __launch_bounds__(BIN_T)
k1_kernel(const int* __restrict__ rows, const int* __restrict__ cols,
          const float* __restrict__ vals, int* __restrict__ lenC,
          uint2* __restrict__ ebinC, int n_edges) {
    __shared__ int lcnt[NBC];     // counts -> running placement pos
    __shared__ int lbase[NBC];    // local exclusive prefix
    __shared__ int garr[NBC];     // reserved global base
    __shared__ int w0sum;
    __shared__ uint2 srec[BIN_CHUNK];      // 16 KB
    __shared__ unsigned char sbkt[BIN_CHUNK];

    const int t = threadIdx.x;
    const int base = blockIdx.x * BIN_CHUNK;

    if (t < NBC) lcnt[t] = 0;
    __syncthreads();

    unsigned int mykey[BIN_EPT];
    float myval[BIN_EPT];
    bool myok[BIN_EPT];
#pragma unroll
    for (int j = 0; j < BIN_EPT; j++) {
        int e = base + j * BIN_T + t;
        myok[j] = (e < n_edges);
        if (myok[j]) {
            int r = rows[e];
            int c = cols[e];
            myval[j] = vals[e];
            mykey[j] = ((unsigned)r << 16) | (unsigned)c;
            atomicAdd(&lcnt[r >> 9], 1);
        }
    }
    __syncthreads();

    // exclusive scan over NBC<=128 buckets: shfl within 2 waves + combine
    const int lane = t & 63;
    int cval = 0, inc = 0;
    if (t < 128) {
        cval = (t < NBC) ? lcnt[t] : 0;
        inc = cval;
#pragma unroll
        for (int d = 1; d < 64; d <<= 1) {
            int u = __shfl_up(inc, d);
            if (lane >= d) inc += u;
        }
        if (t == 63) w0sum = inc;
    }
    __syncthreads();
    if (t >= 64 && t < 128) inc += w0sum;
    if (t < NBC) {
        int lb = inc - cval;
        lbase[t] = lb;
        if (cval > 0) garr[t] = t * SLABC + atomicAdd(&lenC[t], cval);
        lcnt[t] = lb;            // running placement position
    }
    __syncthreads();

#pragma unroll
    for (int j = 0; j < BIN_EPT; j++) {
        if (myok[j]) {
            int b = (int)(mykey[j] >> 25);        // row >> 9
            int p = atomicAdd(&lcnt[b], 1);
            srec[p] = make_uint2(mykey[j], __float_as_uint(myval[j]));
            sbkt[p] = (unsigned char)b;
        }
    }
    __syncthreads();

    const int m = min(BIN_CHUNK, n_edges - base);
    for (int i = t; i < m; i += BIN_T) {
        int b = sbkt[i];
        int dst = garr[b] + (i - lbase[b]);
        if (dst < (b + 1) * SLABC) ebinC[dst] = srec[i];  // overflow guard
    }
}

// ---- splitgemm: blocks [0,NBC) split; blocks [NBC, NBC+GEMM_BLKS) gemm ---
__global__ void __launch_bounds__(SPLIT_T)
splitgemm_kernel(const int* __restrict__ lenC, const uint2* __restrict__ ebinC,
                 uint2* __restrict__ ebin2, int* __restrict__ roff,
                 int* __restrict__ rlen,
                 const float* __restrict__ x, const unsigned short* __restrict__ wt,
                 unsigned short* __restrict__ support, int n_nodes) {
    __shared__ int cnt[SPLIT_T];     // per-row counts (512 rows)
    __shared__ int lb[SPLIT_T];      // exclusive prefix
    __shared__ int pos[SPLIT_T];     // running placement
    __shared__ int wsum[8], wbase[8];
    __shared__ uint2 srec[SLABC];    // 57.5 KB (total ~63.6 KB static LDS)

    const int t = threadIdx.x;

    if ((int)blockIdx.x >= NBC) {
        // ---------------- gemm path: 32 rows per block, 8 waves -----------
        const int gb = blockIdx.x - NBC;
        const int wid = t >> 6;
        const int mt = wid >> 2;             // 0/1: which 16-row m-tile
        const int nw = wid & 3;              // n-group: cols nw*32..nw*32+31
        const int lane = t & 63;
        const int l15 = lane & 15;
        const int lhi = lane >> 4;

        const int m0 = gb * 32 + mt * 16;
        const int n0 = nw * 32;

        int xr = m0 + l15;
        if (xr >= n_nodes) xr = n_nodes - 1;     // clamp OOB loads
        const float* xrow = x + (size_t)xr * F_DIM + lhi * 8;
        const unsigned short* wrow0 = wt + (size_t)(n0 + l15) * F_DIM + lhi * 8;
        const unsigned short* wrow1 = wrow0 + 16 * F_DIM;

        f32x4 acc0 = {0.f, 0.f, 0.f, 0.f};
        f32x4 acc1 = {0.f, 0.f, 0.f, 0.f};
#pragma unroll
        for (int k0 = 0; k0 < F_DIM; k0 += 32) {
            float4 xa = *reinterpret_cast<const float4*>(xrow + k0);
            float4 xb = *reinterpret_cast<const float4*>(xrow + k0 + 4);
            bf16x8 a, b0, b1;
            a[0] = (short)f2bf(xa.x); a[1] = (short)f2bf(xa.y);
            a[2] = (short)f2bf(xa.z); a[3] = (short)f2bf(xa.w);
            a[4] = (short)f2bf(xb.x); a[5] = (short)f2bf(xb.y);
            a[6] = (short)f2bf(xb.z); a[7] = (short)f2bf(xb.w);
            b0 = *reinterpret_cast<const bf16x8*>(wrow0 + k0);
            b1 = *reinterpret_cast<const bf16x8*>(wrow1 + k0);
            acc0 = __builtin_amdgcn_mfma_f32_16x16x32_bf16(a, b0, acc0, 0, 0, 0);
            acc1 = __builtin_amdgcn_mfma_f32_16x16x32_bf16(a, b1, acc1, 0, 0, 0);
        }

        // D: row = m0 + 4*lhi + i, cols n0 + l15 and n0 + 16 + l15
        unsigned short* sp = support + (size_t)(m0 + 4 * lhi) * F_DIM + n0 + l15;
#pragma unroll
        for (int i = 0; i < 4; i++) {
            int row = m0 + 4 * lhi + i;
            if (row < n_nodes) {
                sp[(size_t)i * F_DIM]      = f2bf(acc0[i]);
                sp[(size_t)i * F_DIM + 16] = f2bf(acc1[i]);
            }
        }
        return;
    }

    // ---------------- split path: row-sort one coarse slab + CSR ----------
    const int b = blockIdx.x;
    const int n = min(lenC[b], SLABC);
    const uint2* src = ebinC + (size_t)b * SLABC;

    cnt[t] = 0;
    __syncthreads();

    uint2 myr[SPLIT_EPT];
    int myrow[SPLIT_EPT];
#pragma unroll
    for (int j = 0; j < SPLIT_EPT; j++) {
        int idx = j * SPLIT_T + t;
        myrow[j] = -1;
        if (idx < n) {
            myr[j] = src[idx];
            myrow[j] = (int)((myr[j].x >> 16) & 511u);   // row within slab
            atomicAdd(&cnt[myrow[j]], 1);
        }
    }
    __syncthreads();

    // exclusive scan over 512 counters: wave shfl scans + 8-way combine
    const int lane = t & 63;
    const int wv = t >> 6;
    const int myc = cnt[t];
    int inc = myc;
#pragma unroll
    for (int d = 1; d < 64; d <<= 1) {
        int u = __shfl_up(inc, d);
        if (lane >= d) inc += u;
    }
    if (lane == 63) wsum[wv] = inc;
    __syncthreads();
    if (t == 0) {
        int run = 0;
#pragma unroll
        for (int k = 0; k < 8; k++) { wbase[k] = run; run += wsum[k]; }
    }
    __syncthreads();
    const int excl = wbase[wv] + inc - myc;
    lb[t] = excl;
    pos[t] = excl;
    __syncthreads();

    // place into row-sorted LDS buffer
#pragma unroll
    for (int j = 0; j < SPLIT_EPT; j++) {
        if (myrow[j] >= 0) {
            int p = atomicAdd(&pos[myrow[j]], 1);
            srec[p] = myr[j];
        }
    }
    __syncthreads();

    // fully coalesced flush + CSR
    const int gbase = b * SLABC;
    for (int i = t; i < n; i += SPLIT_T)
        ebin2[gbase + i] = srec[i];
    roff[(b << 9) + t] = gbase + lb[t];
    rlen[(b << 9) + t] = myc;
}

// ---- bspmm: row per HALF-wave; 8-deep masked rounds ----------------------
// Half-wave (32 lanes) owns one row; lane covers 4 bf16 cols (uint2 gather).
// Each round: 8 record loads issue together, then 8 independent gathers ->
// 16 records in flight per wave. Masked tail (clamped idx, zeroed val).
__global__ void __launch_bounds__(256)
bspmm_kernel(const unsigned short* __restrict__ support,
             const uint2* __restrict__ ebin2, const int* __restrict__ roff,
             const int* __restrict__ rlen, const float* __restrict__ bias,
             float* __restrict__ out, int n_nodes) {
    const int wave = blockIdx.x * 4 + (threadIdx.x >> 6);
    const int lane = threadIdx.x & 63;
    const int half = lane >> 5;
    const int l32 = lane & 31;
    const unsigned coff = l32 * 4u;          // 4 bf16 columns per lane
    const int row = wave * 2 + half;
    if (row >= n_nodes) return;

    const int s = roff[row];
    const int n = rlen[row];

    float a0 = 0.f, a1 = 0.f, a2 = 0.f, a3 = 0.f;

#pragma unroll 1
    for (int i = 0; i < n; i += 8) {
        uint2 r[8];
        uint2 sv[8];
        float v[8];
#pragma unroll
        for (int j = 0; j < 8; j++) {
            int idx = i + j;
            r[j] = ebin2[s + (idx < n ? idx : n - 1)];
        }
#pragma unroll
        for (int j = 0; j < 8; j++) {
            sv[j] = *reinterpret_cast<const uint2*>(
                support + (size_t)(r[j].x & 0xffffu) * F_DIM + coff);
            v[j] = (i + j < n) ? __uint_as_float(r[j].y) : 0.f;
        }
#pragma unroll
        for (int j = 0; j < 8; j++) {
            a0 += v[j] * __uint_as_float(sv[j].x << 16);
            a1 += v[j] * __uint_as_float(sv[j].x & 0xFFFF0000u);
            a2 += v[j] * __uint_as_float(sv[j].y << 16);
            a3 += v[j] * __uint_as_float(sv[j].y & 0xFFFF0000u);
        }
    }

    const float4 bb = *reinterpret_cast<const float4*>(bias + coff);
    float4 o = make_float4(a0 + bb.x, a1 + bb.y, a2 + bb.z, a3 + bb.w);
    *reinterpret_cast<float4*>(out + (size_t)row * F_DIM + coff) = o;
}

extern "C" void kernel_launch(void* const* d_in, const int* in_sizes, int n_in,
                              void* d_out, int out_size, void* d_ws, size_t ws_size,
                              hipStream_t stream) {
    const float* x      = (const float*)d_in[0];
    const float* weight = (const float*)d_in[1];
    const float* bias   = (const float*)d_in[2];
    const float* evals  = (const float*)d_in[3];
    const int*   erows  = (const int*)d_in[4];
    const int*   ecols  = (const int*)d_in[5];
    float* out = (float*)d_out;

    const int n_nodes = in_sizes[0] / F_DIM;   // 50000
    const int n_edges = in_sizes[3];           // 625000

    // Workspace layout (~25 MB)
    unsigned short* support = (unsigned short*)d_ws;                  // 12.8 MB
    unsigned short* wt      = support + (size_t)n_nodes * F_DIM;      // 32 KB
    int* lenC = (int*)(wt + F_DIM * F_DIM);                           // 128
    int* roff = lenC + 128;                                           // 50176
    int* rlen = roff + NROW_PAD;                                      // 50176
    uintptr_t ep = (uintptr_t)(rlen + NROW_PAD);
    ep = (ep + 15) & ~(uintptr_t)15;
    uint2* ebinC = (uint2*)ep;                                        // 5.77 MB
    uint2* ebin2 = ebinC + (size_t)NBC * SLABC;                       // 5.77 MB

    // 1) wconv + zero lenC
    init_kernel<<<65, 256, 0, stream>>>(weight, wt, lenC);

    // 2) coarse bin (306 blocks)
    int nbin = (n_edges + BIN_CHUNK - 1) / BIN_CHUNK;                 // 306
    k1_kernel<<<nbin, BIN_T, 0, stream>>>(erows, ecols, evals, lenC,
                                          ebinC, n_edges);

    // 3) merged: split (98 blocks) || gemm (1563 blocks)
    splitgemm_kernel<<<NBC + GEMM_BLKS, SPLIT_T, 0, stream>>>(
        lenC, ebinC, ebin2, roff, rlen, x, wt, support, n_nodes);

    // 4) row-per-half-wave pull-spmm over CSR: 16 records in flight/wave
    int waves = (n_nodes + 1) / 2;                                    // 25000
    bspmm_kernel<<<(waves + 3) / 4, 256, 0, stream>>>(support, ebin2, roff,
                                                      rlen, bias, out, n_nodes);
}